// Round 10
// baseline (2331.895 us; speedup 1.0000x reference)
//
#include <hip/hip_runtime.h>

// CRF forward chain on MI355X — linearized: u' = (1/g) diag(exp(h_s)) E u.
// R16 = R15 + signed-zero tag fix. R15's deadlock: row START is identically 0
// (E[START,:]=exp(NEG)=0) and folding the input sign into the output scale
// made stored zeros carry the WRONG sign tag (+0*(-1/m) = -0.0) at T%4 in
// {2,3} -> consumers spun forever on one dword. Fix: store magnitudes
// (|rA| e^h kappa/m, sign bits provably clear) and FORCE the tag with
// integer OR (0x80008000) — tag correct for all values including zeros.
// Structure (unchanged from R15): producer-packed f16 u~ (1024 dwords/chain,
// 4KB): poll = 4x dwordx4/wave (half of R14), polled regs feed fdot2
// DIRECTLY (no consumer pack, no LDS broadcast), m = max|u~| by exact
// integer max on f16 bits (all waves bitwise-identical), NO BARRIERS in the
// main loop — waves free-run on the sign-tag dataflow; skew = latency
// hiding. 2-chain interleave (issue Y poll before X GEMV) hides poll RT.
// Bookkeeping: u~(t+1) = kappa*(E*(u~(t)/m_t))*exp(h); Chat += log(m/kappa);
// invariant M*usave = ufin*exp(Chat) — stitch telescopes as in R10-R14.
// NCH=32, CH_LEN=256, BURN=24, TCYC=280. 256 blocks = 1/CU (proven regime).
//
// ws layout: u~ uint[32][2][1024] @0 (256KB); usave f32[32][2048] @262144;
// ufin f32[32][2048] @524288; cbuf f32[32] @786432; posts int[2048] @786688.

#define TSZ   2048
#define NCH   32
#define NW    8
#define CH_LEN 256
#define BURN  24
#define TCYC  (CH_LEN + BURN)
#define START_I 0
#define END_I   1
#define KAPPA 0.00390625f   // 2^-8

typedef float v4f __attribute__((ext_vector_type(4)));
typedef unsigned v4u __attribute__((ext_vector_type(4)));
typedef _Float16 h2f __attribute__((ext_vector_type(2)));

__device__ __forceinline__ h2f pk16(float a, float b) {
    return __builtin_bit_cast(h2f, __builtin_amdgcn_cvt_pkrtz(a, b));
}
__device__ __forceinline__ void st_coh(float* p, float v) {
    asm volatile("global_store_dword %0, %1, off sc0 sc1"
                 :: "v"(p), "v"(v) : "memory");
}
__device__ __forceinline__ void st_cohu(unsigned* p, unsigned v) {
    asm volatile("global_store_dword %0, %1, off sc0 sc1"
                 :: "v"(p), "v"(v) : "memory");
}
__device__ __forceinline__ float ld_coh1(const float* p) {
    float r;
    asm volatile("global_load_dword %0, %1, off sc0 sc1\n\ts_waitcnt vmcnt(0)"
                 : "=&v"(r) : "v"(p) : "memory");
    return r;
}
__device__ __forceinline__ v4f ld_coh4(const float* p) {
    v4f r;
    asm volatile("global_load_dwordx4 %0, %1, off sc0 sc1\n\ts_waitcnt vmcnt(0)"
                 : "=&v"(r) : "v"(p) : "memory");
    return r;
}

// issue 4x dwordx4 (16 dwords = full 4KB u~ slice for this lane), NO wait
#define ISSUE4(R0,R1,R2,R3,P)                                                 \
    asm volatile(                                                             \
        "global_load_dwordx4 %0, %4, off sc0 sc1\n\t"                         \
        "global_load_dwordx4 %1, %4, off offset:1024 sc0 sc1\n\t"             \
        "global_load_dwordx4 %2, %4, off offset:2048 sc0 sc1\n\t"             \
        "global_load_dwordx4 %3, %4, off offset:3072 sc0 sc1"                 \
        : "=&v"(R0), "=&v"(R1), "=&v"(R2), "=&v"(R3)                          \
        : "v"(P) : "memory")

// re-issue + wait (retry path)
#define RELOAD4(R0,R1,R2,R3,P)                                                \
    asm volatile(                                                             \
        "global_load_dwordx4 %0, %4, off sc0 sc1\n\t"                         \
        "global_load_dwordx4 %1, %4, off offset:1024 sc0 sc1\n\t"             \
        "global_load_dwordx4 %2, %4, off offset:2048 sc0 sc1\n\t"             \
        "global_load_dwordx4 %3, %4, off offset:3072 sc0 sc1\n\t"             \
        "s_waitcnt vmcnt(0)"                                                  \
        : "=&v"(R0), "=&v"(R1), "=&v"(R2), "=&v"(R3)                          \
        : "v"(P) : "memory")

// wait for issued loads, then spin until all 16 dwords carry tag INNEG
#define WAITFRESH(R0,R1,R2,R3,P,INNEG)                                        \
    do {                                                                      \
        asm volatile("s_waitcnt vmcnt(0)"                                     \
                     : "+v"(R0), "+v"(R1), "+v"(R2), "+v"(R3) :: "memory");   \
        for (;;) {                                                            \
            unsigned am_ = 0xffffffffu, om_ = 0u;                             \
            _Pragma("unroll")                                                 \
            for (int d_ = 0; d_ < 4; ++d_) {                                  \
                unsigned t_;                                                  \
                t_ = R0[d_] & 0x80008000u; am_ &= t_; om_ |= t_;              \
                t_ = R1[d_] & 0x80008000u; am_ &= t_; om_ |= t_;              \
                t_ = R2[d_] & 0x80008000u; am_ &= t_; om_ |= t_;              \
                t_ = R3[d_] & 0x80008000u; am_ &= t_; om_ |= t_;              \
            }                                                                 \
            bool fr_ = (INNEG) ? (am_ == 0x80008000u) : (om_ == 0u);          \
            if (__all(fr_)) break;                                            \
            RELOAD4(R0, R1, R2, R3, P);                                       \
        }                                                                     \
    } while (0)

__global__ __launch_bounds__(512, 1)
void crf_chain(const float* __restrict__ h, const float* __restrict__ tr,
               float* __restrict__ out, float* __restrict__ ws)
{
    const int tid  = threadIdx.x;
    const int lane = tid & 63;
    const int wv   = tid >> 6;          // 0..7
    const int blk  = blockIdx.x;
    const int g    = blk >> 4;          // group 0..15
    const int b    = blk & 15;          // block within group 0..15
    const int ca   = g;                 // chain X chunk 0..15
    const int cb   = g + 16;            // chain Y chunk 16..31
    const int row_base = b * 128 + wv * 16;

    unsigned* ub   = (unsigned*)ws;                   // [32][2][1024] f16x2
    float* wsf     = (float*)ws;
    float* usave   = wsf + 65536;                     // [32][2048]
    float* ufin    = usave + NCH * TSZ;               // [32][2048]
    float* cbuf    = ufin + NCH * TSZ;                // [32]
    int*   posts   = (int*)(wsf + 196672);            // [2048] @ byte 786688

    __shared__ unsigned long long els64[32][512];     // 4 LDS E-rows/wave, 128KB

    // ---- one-time: register E fragment, 12 rows/wave, packed-u layout:
    // uh[j] = u~ dword D = 4*lane + 256*(j>>2) + (j&3), holding rows
    // (16*(D>>3)+(D&7), +8). e2r[r][j] = pk16(exp(tr[row][c]), exp(tr[row][c+8])).
    h2f e2r[12][16];
    #pragma unroll
    for (int r = 0; r < 12; ++r) {
        const float* trow = tr + (size_t)(row_base + r) * TSZ;
        #pragma unroll
        for (int j = 0; j < 16; ++j) {
            int D = 4 * lane + 256 * (j >> 2) + (j & 3);
            int c = 16 * (D >> 3) + (D & 7);
            e2r[r][j] = pk16(__expf(trow[c]), __expf(trow[c + 8]));
        }
    }
    // ---- one-time: LDS E rows 12..15/wave; u64 unit k pairs (uh[2k], uh[2k+1])
    #pragma unroll
    for (int rr = 0; rr < 4; ++rr) {
        const float* trow = tr + (size_t)(row_base + 12 + rr) * TSZ;
        #pragma unroll
        for (int k = 0; k < 8; ++k) {
            int j0 = 2 * k, j1 = 2 * k + 1;
            int D0 = 4 * lane + 256 * (j0 >> 2) + (j0 & 3);
            int D1 = 4 * lane + 256 * (j1 >> 2) + (j1 & 3);
            int c0 = 16 * (D0 >> 3) + (D0 & 7);
            int c1 = 16 * (D1 >> 3) + (D1 & 7);
            unsigned lo = __builtin_bit_cast(unsigned, pk16(__expf(trow[c0]), __expf(trow[c0 + 8])));
            unsigned hi = __builtin_bit_cast(unsigned, pk16(__expf(trow[c1]), __expf(trow[c1 + 8])));
            els64[wv * 4 + rr][lane + 64 * k] =
                ((unsigned long long)hi << 32) | (unsigned long long)lo;
        }
    }

    const int q    = ((lane & 1) << 2) | (lane & 2) | ((lane >> 2) & 1);
    const int grow = row_base + q;          // rows grow, grow+8 for lane<8

    // chain schedules
    const int skX = ca * CH_LEN, seX = skX + CH_LEN;
    const int s0X = (ca == 0) ? 0 : (skX - BURN);
    const int TX  = (ca == 0) ? CH_LEN : TCYC;
    const int skY = cb * CH_LEN, seY = skY + CH_LEN;
    const int s0Y = skY - BURN;

    unsigned* ubX = ub + ca * 2 * 1024;     // parity p at +p*1024 dwords
    unsigned* ubY = ub + cb * 2 * 1024;

    // ---- init: u~(0) = kappa * (one-hot | ones), parity 0, POSITIVE tag.
    // dword j holds rows (16*(j>>3)+(j&7), +8). Idempotent across blocks.
    for (int j = tid; j < 1024; j += 512) {
        int rlo = 16 * (j >> 3) + (j & 7), rhi = rlo + 8;
        float xa = (ca == 0) ? ((rlo == START_I) ? KAPPA : 0.0f) : KAPPA;
        float xb = (ca == 0) ? ((rhi == START_I) ? KAPPA : 0.0f) : KAPPA;
        st_cohu(&ubX[j], __builtin_bit_cast(unsigned, pk16(xa, xb)));
        st_cohu(&ubY[j], __builtin_bit_cast(unsigned, pk16(KAPPA, KAPPA)));
    }
    __syncthreads();   // els64 visible; only barrier in the whole kernel

    float ChatX = 0.0f, ChatY = 0.0f;

    // ---- exact max|u~| via integer max on f16 bit patterns (all waves identical)
    auto MAXRED = [&](v4u a0, v4u a1, v4u a2, v4u a3) -> float {
        unsigned mm = 0;
        #pragma unroll
        for (int d = 0; d < 4; ++d) {
            unsigned a;
            a = a0[d] & 0x7fff7fffu; mm = mm > (a & 0xffffu) ? mm : (a & 0xffffu); mm = mm > (a >> 16) ? mm : (a >> 16);
            a = a1[d] & 0x7fff7fffu; mm = mm > (a & 0xffffu) ? mm : (a & 0xffffu); mm = mm > (a >> 16) ? mm : (a >> 16);
            a = a2[d] & 0x7fff7fffu; mm = mm > (a & 0xffffu) ? mm : (a & 0xffffu); mm = mm > (a >> 16) ? mm : (a >> 16);
            a = a3[d] & 0x7fff7fffu; mm = mm > (a & 0xffffu) ? mm : (a & 0xffffu); mm = mm > (a >> 16) ? mm : (a >> 16);
        }
        #pragma unroll
        for (int d = 1; d < 64; d <<= 1) {
            unsigned o = (unsigned)__shfl_xor((int)mm, d, 64);
            mm = mm > o ? mm : o;
        }
        _Float16 hf = __builtin_bit_cast(_Float16, (unsigned short)mm);
        return (float)hf;
    };

    // ---- GEMV (16 rows/wave: 12 reg + 4 LDS) on packed f16 input regs
    auto GEMV = [&](v4u a0, v4u a1, v4u a2, v4u a3, float& oA, float& oB) {
        h2f uh[16];
        #pragma unroll
        for (int d = 0; d < 4; ++d) {
            uh[d]      = __builtin_bit_cast(h2f, a0[d]);
            uh[4 + d]  = __builtin_bit_cast(h2f, a1[d]);
            uh[8 + d]  = __builtin_bit_cast(h2f, a2[d]);
            uh[12 + d] = __builtin_bit_cast(h2f, a3[d]);
        }
        float acc[8];
        #pragma unroll
        for (int r = 0; r < 8; ++r) acc[r] = 0.0f;
        #pragma unroll
        for (int k = 0; k < 16; ++k) {
            #pragma unroll
            for (int r = 0; r < 8; ++r)
                acc[r] = __builtin_amdgcn_fdot2(e2r[r][k], uh[k], acc[r], false);
        }
        #pragma unroll
        for (int r = 0; r < 4; ++r) {
            float send = (lane & 1) ? acc[r] : acc[r + 4];
            float recv = __shfl_xor(send, 1, 64);
            float keep = (lane & 1) ? acc[r + 4] : acc[r];
            acc[r] = keep + recv;
        }
        #pragma unroll
        for (int r = 0; r < 2; ++r) {
            float send = (lane & 2) ? acc[r] : acc[r + 2];
            float recv = __shfl_xor(send, 2, 64);
            float keep = (lane & 2) ? acc[r + 2] : acc[r];
            acc[r] = keep + recv;
        }
        {
            float send = (lane & 4) ? acc[0] : acc[1];
            float recv = __shfl_xor(send, 4, 64);
            float keep = (lane & 4) ? acc[1] : acc[0];
            acc[0] = keep + recv;
        }
        acc[0] += __shfl_xor(acc[0], 8, 64);
        acc[0] += __shfl_xor(acc[0], 16, 64);
        acc[0] += __shfl_xor(acc[0], 32, 64);
        oA = acc[0];

        #pragma unroll
        for (int r = 0; r < 8; ++r) acc[r] = 0.0f;
        #pragma unroll
        for (int k = 0; k < 8; ++k) {
            unsigned long long q0 = els64[wv * 4 + 0][lane + 64 * k];
            unsigned long long q1 = els64[wv * 4 + 1][lane + 64 * k];
            unsigned long long q2 = els64[wv * 4 + 2][lane + 64 * k];
            unsigned long long q3 = els64[wv * 4 + 3][lane + 64 * k];
            #pragma unroll
            for (int r = 0; r < 4; ++r) {
                acc[r] = __builtin_amdgcn_fdot2(e2r[8 + r][2 * k],     uh[2 * k],     acc[r], false);
                acc[r] = __builtin_amdgcn_fdot2(e2r[8 + r][2 * k + 1], uh[2 * k + 1], acc[r], false);
            }
            acc[4] = __builtin_amdgcn_fdot2(__builtin_bit_cast(h2f, (unsigned)q0),         uh[2 * k],     acc[4], false);
            acc[4] = __builtin_amdgcn_fdot2(__builtin_bit_cast(h2f, (unsigned)(q0 >> 32)), uh[2 * k + 1], acc[4], false);
            acc[5] = __builtin_amdgcn_fdot2(__builtin_bit_cast(h2f, (unsigned)q1),         uh[2 * k],     acc[5], false);
            acc[5] = __builtin_amdgcn_fdot2(__builtin_bit_cast(h2f, (unsigned)(q1 >> 32)), uh[2 * k + 1], acc[5], false);
            acc[6] = __builtin_amdgcn_fdot2(__builtin_bit_cast(h2f, (unsigned)q2),         uh[2 * k],     acc[6], false);
            acc[6] = __builtin_amdgcn_fdot2(__builtin_bit_cast(h2f, (unsigned)(q2 >> 32)), uh[2 * k + 1], acc[6], false);
            acc[7] = __builtin_amdgcn_fdot2(__builtin_bit_cast(h2f, (unsigned)q3),         uh[2 * k],     acc[7], false);
            acc[7] = __builtin_amdgcn_fdot2(__builtin_bit_cast(h2f, (unsigned)(q3 >> 32)), uh[2 * k + 1], acc[7], false);
        }
        #pragma unroll
        for (int r = 0; r < 4; ++r) {
            float send = (lane & 1) ? acc[r] : acc[r + 4];
            float recv = __shfl_xor(send, 1, 64);
            float keep = (lane & 1) ? acc[r + 4] : acc[r];
            acc[r] = keep + recv;
        }
        #pragma unroll
        for (int r = 0; r < 2; ++r) {
            float send = (lane & 2) ? acc[r] : acc[r + 2];
            float recv = __shfl_xor(send, 2, 64);
            float keep = (lane & 2) ? acc[r + 2] : acc[r];
            acc[r] = keep + recv;
        }
        {
            float send = (lane & 4) ? acc[0] : acc[1];
            float recv = __shfl_xor(send, 4, 64);
            float keep = (lane & 4) ? acc[1] : acc[0];
            acc[0] = keep + recv;
        }
        acc[0] += __shfl_xor(acc[0], 8, 64);
        acc[0] += __shfl_xor(acc[0], 16, 64);
        acc[0] += __shfl_xor(acc[0], 32, 64);
        oB = acc[0];
    };

    const int outD = 64 * b + 8 * wv + q;   // my output dword index (lane<8)

    v4u x0, x1, x2, x3, y0, y1, y2, y3;
    const unsigned* pX0 = ubX + 4 * lane;            // parity 0 poll base
    const unsigned* pX1 = ubX + 1024 + 4 * lane;     // parity 1
    const unsigned* pY0 = ubY + 4 * lane;
    const unsigned* pY1 = ubY + 1024 + 4 * lane;

    // ---- prologue: issue X(0) poll
    ISSUE4(x0, x1, x2, x3, pX0);

    for (int T = 0; T < TCYC; ++T) {
        const int outp = (T + 1) & 1, outn = ((T + 1) >> 1) & 1;
        const int inn  = (T >> 1) & 1;
        const unsigned tagbits = outn ? 0x80008000u : 0u;
        const unsigned* pXin = (T & 1) ? pX1 : pX0;
        const unsigned* pYin = (T & 1) ? pY1 : pY0;

        // -------- X phase: consume X(T), store X(T+1) --------
        const bool doX = (T < TX);
        if (doX) {
            const int sX = s0X + T;
            float h0 = 0.0f, h1 = 0.0f;
            if (lane < 8) {
                h0 = h[(size_t)sX * TSZ + grow];
                h1 = h[(size_t)sX * TSZ + grow + 8];
            }
            WAITFRESH(x0, x1, x2, x3, pXin, inn);
            ISSUE4(y0, y1, y2, y3, pYin);            // Y(T) poll hides under X GEMV
            float mX = MAXRED(x0, x1, x2, x3);
            float rA, rB;
            GEMV(x0, x1, x2, x3, rA, rB);
            if (lane < 8) {
                // |rA| = true (nonnegative) value regardless of input sign tag;
                // tag forced by integer OR (handles zeros exactly — R15 fix).
                float invm = 1.0f / mX;
                float PA = fabsf(rA) * __expf(h0) * invm;
                float PB = fabsf(rB) * __expf(h1) * invm;
                unsigned w = __builtin_bit_cast(unsigned, pk16(PA * KAPPA, PB * KAPPA)) | tagbits;
                st_cohu(&ubX[outp * 1024 + outD], w);
                if (ca > 0 && sX + 1 == skX) {
                    st_coh(&usave[ca * TSZ + grow],     PA);
                    st_coh(&usave[ca * TSZ + grow + 8], PB);
                }
                if (sX + 1 == seX) {
                    st_coh(&ufin[ca * TSZ + grow],     PA);
                    st_coh(&ufin[ca * TSZ + grow + 8], PB);
                }
            }
            if (sX + 1 > skX) ChatX += __logf(mX * 256.0f);   // log(m/kappa)
        } else {
            ISSUE4(y0, y1, y2, y3, pYin);
        }

        // -------- Y phase: consume Y(T), store Y(T+1) --------
        {
            const int sY = s0Y + T;
            float h0 = 0.0f, h1 = 0.0f;
            if (lane < 8) {
                h0 = h[(size_t)sY * TSZ + grow];
                h1 = h[(size_t)sY * TSZ + grow + 8];
            }
            WAITFRESH(y0, y1, y2, y3, pYin, inn);
            if (T + 1 < TX) {                        // X(T+1) poll hides under Y GEMV
                const unsigned* pXn = ((T + 1) & 1) ? pX1 : pX0;
                ISSUE4(x0, x1, x2, x3, pXn);
            }
            float mY = MAXRED(y0, y1, y2, y3);
            float rA, rB;
            GEMV(y0, y1, y2, y3, rA, rB);
            if (lane < 8) {
                float invm = 1.0f / mY;
                float PA = fabsf(rA) * __expf(h0) * invm;
                float PB = fabsf(rB) * __expf(h1) * invm;
                unsigned w = __builtin_bit_cast(unsigned, pk16(PA * KAPPA, PB * KAPPA)) | tagbits;
                st_cohu(&ubY[outp * 1024 + outD], w);
                if (sY + 1 == skY) {
                    st_coh(&usave[cb * TSZ + grow],     PA);
                    st_coh(&usave[cb * TSZ + grow + 8], PB);
                }
                if (sY + 1 == seY) {
                    st_coh(&ufin[cb * TSZ + grow],     PA);
                    st_coh(&ufin[cb * TSZ + grow + 8], PB);
                }
            }
            if (sY + 1 > skY) ChatY += __logf(mY * 256.0f);
        }
    }

    // ---- completion: store Chats, ack all stores, per-wave post
    if (b == 0 && wv == 0 && lane == 0) {
        st_coh(&cbuf[ca], ChatX);
        st_coh(&cbuf[cb], ChatY);
    }
    asm volatile("s_waitcnt vmcnt(0)" ::: "memory");
    if (lane == 0)
        __hip_atomic_store(&posts[blk * NW + wv], 1,
                           __ATOMIC_RELAXED, __HIP_MEMORY_SCOPE_AGENT);

    // ---- finisher: block 0 / wave 0 stitches 32 chunks
    if (blk == 0 && wv == 0) {
        int ok;
        do {
            __builtin_amdgcn_s_sleep(1);
            ok = 1;
            #pragma unroll
            for (int i = 0; i < 32; ++i) {     // 256 blocks x 8 waves = 2048
                int v = __hip_atomic_load(&posts[lane + 64 * i],
                                          __ATOMIC_RELAXED, __HIP_MEMORY_SCOPE_AGENT);
                ok &= (v == 1);
            }
        } while (!__all(ok));

        float O = 0.0f;
        for (int cc = 1; cc < NCH; ++cc) {
            float sa = 0.0f, sb = 0.0f;
            for (int j = 4 * lane; j < TSZ; j += 256) {
                v4f a4 = ld_coh4(&ufin[(cc - 1) * TSZ + j]);
                v4f b4 = ld_coh4(&usave[cc * TSZ + j]);
                sa += a4.x + a4.y + a4.z + a4.w;
                sb += b4.x + b4.y + b4.z + b4.w;
            }
            #pragma unroll
            for (int d = 1; d < 64; d <<= 1) {
                sa += __shfl_xor(sa, d, 64);
                sb += __shfl_xor(sb, d, 64);
            }
            O += ld_coh1(&cbuf[cc - 1]) + __logf(sa) - __logf(sb);
        }
        float se = 0.0f;
        for (int j = 4 * lane; j < TSZ; j += 256) {
            const float4 t4 = *(const float4*)(tr + (size_t)END_I * TSZ + j);
            v4f uf = ld_coh4(&ufin[(NCH - 1) * TSZ + j]);
            se += __expf(t4.x) * uf.x + __expf(t4.y) * uf.y +
                  __expf(t4.z) * uf.z + __expf(t4.w) * uf.w;
        }
        #pragma unroll
        for (int d = 1; d < 64; d <<= 1) se += __shfl_xor(se, d, 64);

        float ans = O + ld_coh1(&cbuf[NCH - 1]) + __logf(se);
        if (lane == 0) out[0] = ans;
    }
}

extern "C" void kernel_launch(void* const* d_in, const int* in_sizes, int n_in,
                              void* d_out, int out_size, void* d_ws, size_t ws_size,
                              hipStream_t stream) {
    const float* h  = (const float*)d_in[0];   // [8192, 2048] fp32 emissions
    const float* tr = (const float*)d_in[1];   // [2048, 2048] fp32 transitions
    (void)in_sizes; (void)n_in; (void)out_size; (void)ws_size;
    crf_chain<<<dim3(256), dim3(512), 0, stream>>>(h, tr, (float*)d_out, (float*)d_ws);
}